// Round 8
// baseline (99871.179 us; speedup 1.0000x reference)
//
#include <hip/hip_runtime.h>
#include <math.h>

// ---- static dims ----
#define B8      8
#define LSEQ    512
#define NWG     256
#define TPB     512
#define RELK    97
#define BI      148
#define FSTR    16        // barrier line stride (ints) = 64B
#define XIP     10312     // padded xi stride (floats, even)

// LDS float offsets
#define oWA     0         // [288][64]   18432
#define oW1     18432     // [64][32]     2048
#define oW2     20480     // [64][32]     2048
#define oWX     22528     // [48][256]   12288
#define oWY     34816     // [68][35]     2380
#define oST     37196     // stage/scratch 3752
#define LDSF    40948
#define LDSB    (LDSF*4)  // 163792 B

__device__ __forceinline__ float sigf(float x){
  return (x >= 0.f) ? 1.f/(1.f + expf(-x)) : expf(x)/(1.f + expf(x));
}
__device__ __forceinline__ float spf(float x){
  return (x > 0.f) ? x + log1pf(expf(-x)) : log1pf(expf(x));
}
// agent-scope (L3-coherent) transfers for cross-wg data
__device__ __forceinline__ float agld(const float* p){
  return __hip_atomic_load(p, __ATOMIC_RELAXED, __HIP_MEMORY_SCOPE_AGENT);
}
__device__ __forceinline__ void agst(float* p, float v){
  __hip_atomic_store(p, v, __ATOMIC_RELAXED, __HIP_MEMORY_SCOPE_AGENT);
}
__device__ __forceinline__ float2 agld2(const float* p){
  union{ unsigned long long u; float2 f; } c;
  c.u = __hip_atomic_load((const unsigned long long*)p, __ATOMIC_RELAXED, __HIP_MEMORY_SCOPE_AGENT);
  return c.f;
}
__device__ __forceinline__ void agst2(float* p, float2 v){
  union{ unsigned long long u; float2 f; } c; c.f = v;
  __hip_atomic_store((unsigned long long*)p, c.u, __ATOMIC_RELAXED, __HIP_MEMORY_SCOPE_AGENT);
}
// padded xi layout: section starts rounded up to multiples of 4 (all even)
__device__ __forceinline__ int ximap(int c){
  if (c < 4617)  return c;        // rk, rb, wk, wb
  if (c < 5641)  return c+3;      // er(4620), wv(5132)
  if (c < 5650)  return c+3;      // fg(5644), ga(5652)
  if (c < 5651)  return c+6;      // gw(5656)
  return c+9;                     // rm(5660), wmask(5684), rmask(6196), sf(10292), sb(10300)
}

// ---------------------------------------------------------------- sent gather
__global__ __launch_bounds__(256)
void k_sent(const int* __restrict__ cidx, const int* __restrict__ pos,
            const int* __restrict__ ner, const float* __restrict__ wemb,
            const float* __restrict__ eemb, const float* __restrict__ nemb,
            float* __restrict__ sent)
{
  int flat = blockIdx.x*256 + threadIdx.x;
  if (flat >= B8*LSEQ*140) return;
  int d = flat % 140; int bl = flat / 140;
  float v;
  if (d < 100)      v = wemb[(size_t)cidx[bl]*100 + d];
  else if (d < 120) v = eemb[(size_t)pos[bl]*20 + (d-100)];
  else              v = nemb[(size_t)ner[bl]*20 + (d-120)];
  sent[flat] = v;
}

// ------------------------------------------- weight transpose (once, WXI)
__global__ __launch_bounds__(256)
void k_tr(const float* __restrict__ A, const float* __restrict__ Bsrc,
          int N, int K1a, int K1b, int K2, long long total, float* __restrict__ T)
{
  long long i = (long long)blockIdx.x*256 + threadIdx.x;
  if (i >= total) return;
  int k = (int)(i % K2);
  long long c = i / K2;
  float v = 0.f;
  if (k < K1a)            v = A[(size_t)k*N + c];
  else if (k < K1a+K1b)   v = Bsrc[(size_t)(k-K1a)*N + c];
  T[i] = v;
}

// ---------------------------------------------------------- global barrier
// counter-based: one fetch_add; LAST arriver detects locally and broadcasts
// 32 replicated gen lines (<=8 pollers/line). No gather hop, no fences.
__device__ __forceinline__ void gbar(int* cnt, int* genrep, int seq){
  __syncthreads();
  if (threadIdx.x == 0){
    asm volatile("s_waitcnt vmcnt(0)" ::: "memory");
    int prev = __hip_atomic_fetch_add(cnt, 1, __ATOMIC_ACQ_REL, __HIP_MEMORY_SCOPE_AGENT);
    if (prev == seq*NWG - 1){
      #pragma unroll
      for (int i=0;i<32;i++)
        __hip_atomic_store(&genrep[i*FSTR], seq, __ATOMIC_RELAXED, __HIP_MEMORY_SCOPE_AGENT);
    } else {
      while (__hip_atomic_load(&genrep[(blockIdx.x & 31)*FSTR], __ATOMIC_RELAXED, __HIP_MEMORY_SCOPE_AGENT) < seq)
        __builtin_amdgcn_s_sleep(1);
    }
  }
  __syncthreads();
}

// ------------------------------------- per-sample DNC memory addressing phase
// scratch <= 3712 floats inside the 3752-float stage region; xi uses PADDED layout
__device__ void mem_phase(float* lds, const float* __restrict__ xi,
                          float* __restrict__ M, float* u_g, float* ww_g,
                          float* p_g, float* wr_g, float* L_g, float* rout)
{
  const int tid = threadIdx.x;
  float* mL  = lds;          // [32][32] (reused as q1b/q2b after L writeback)
  float* mwr = lds+1024;     // [8][32]
  float* mwrn= lds+1280;
  float* mcr = lds+1536;
  float* mfw = lds+1792;
  float* mbw = lds+2048;
  float* PSI = lds+2304;
  float* UU  = lds+2336;
  float* US  = lds+2368;
  float* AA  = lds+2400;
  float* CW  = lds+2432;
  float* WWN = lds+2464;
  float* WWO = lds+2496;
  float* PP  = lds+2528;
  int*   mord= (int*)(lds+2560);   // 32 ints
  float* mh  = lds+2592;           // rb[0..7] sf[8..15] sb[16..23] fg[24..31]
  float* mpi = lds+2624;           // [8][3]
  float* msc = lds+2648;           // 40 scalars
  float* q1  = lds+2688;           // 512 (head-a key)
  float* q2  = lds+3200;           // 512 (head-a mask), end 3712
  float* q1b = lds;                // 512 (head-b key, after L writeback)
  float* q2b = lds+512;            // 512

  if (tid < 8){
    mh[tid]    = 1.f + spf(agld(&xi[4096+tid]));
    mh[8+tid]  = 1.f + spf(agld(&xi[10292+tid]));
    mh[16+tid] = 1.f + spf(agld(&xi[10300+tid]));
    mh[24+tid] = sigf(agld(&xi[5644+tid]));
    float e0=agld(&xi[5660+3*tid]), e1=agld(&xi[5661+3*tid]), e2=agld(&xi[5662+3*tid]);
    float mx=fmaxf(e0,fmaxf(e1,e2));
    float x0=expf(e0-mx), x1=expf(e1-mx), x2=expf(e2-mx);
    float inv=1.f/(x0+x1+x2);
    mpi[tid*3]=x0*inv; mpi[tid*3+1]=x1*inv; mpi[tid*3+2]=x2*inv;
  }
  if (tid==0){ msc[0]=1.f+spf(agld(&xi[4616])); msc[1]=sigf(agld(&xi[5652])); msc[2]=sigf(agld(&xi[5656])); }
  if (tid<32){ UU[tid]=u_g[tid]; WWO[tid]=ww_g[tid]; PP[tid]=p_g[tid]; }
  if (tid<256) mwr[tid]=wr_g[tid];
  mL[tid]=L_g[tid]; mL[tid+512]=L_g[tid+512];
  if (tid<256){
    float2 wmv=agld2(&xi[5684+2*tid]);
    float2 wkv=agld2(&xi[4104+2*tid]);
    float wm0=0.1f+0.9f*sigf(wmv.x), wm1=0.1f+0.9f*sigf(wmv.y);
    q1[2*tid]=wkv.x*wm0; q1[2*tid+1]=wkv.y*wm1;
    q2[2*tid]=wm0;       q2[2*tid+1]=wm1;
  }
  __syncthreads();

  // psi, usage
  if (tid<32){
    float psi=1.f;
    #pragma unroll
    for (int r=0;r<8;r++) psi *= (1.f - mh[24+r]*mwr[r*32+tid]);
    PSI[tid]=psi;
    float uo=UU[tid], wo=WWO[tid];
    UU[tid]=(uo+wo-uo*wo)*psi;
  }
  __syncthreads();
  // stable ascending argsort of u
  if (tid<32){
    float un=UU[tid]; int rank=0;
    for (int m=0;m<32;m++){ float um=UU[m]; rank += (um<un)||(um==un && m<tid); }
    mord[rank]=tid;
  }
  __syncthreads();
  if (tid<32) US[tid]=UU[mord[tid]];
  __syncthreads();
  if (tid==0){ float cp=1.f; for (int j=0;j<32;j++){ AA[mord[j]]=(1.f-US[j])*cp; cp*=US[j]; } }
  __syncthreads();

  // write content weighting cw (OLD M)
  { float q=q1[tid]*q1[tid];
    for (int o=32;o;o>>=1) q += __shfl_down(q,o,64);
    if ((tid&63)==0) msc[8+(tid>>6)]=q; }
  __syncthreads();
  if (tid==0){ float q=0.f; for (int i=0;i<8;i++) q+=msc[8+i]; msc[3]=sqrtf(q); }
  __syncthreads();
  { int n=tid>>4, wsub=tid&15;
    float d=0.f,q=0.f;
    for (int i=0;i<32;i++){ int w=wsub+16*i; float m=M[(size_t)n*512+w]; float t2=m*q2[w]; d+=q1[w]*t2; q+=t2*t2; }
    for (int o=8;o;o>>=1){ d+=__shfl_down(d,o,16); q+=__shfl_down(q,o,16); }
    if (wsub==0){ float cs=d/(msc[3]*sqrtf(q)+1e-6f); CW[n]=msc[0]*cs; } }
  __syncthreads();
  if (tid==0){ float mx=-1e30f; for(int n=0;n<32;n++) mx=fmaxf(mx,CW[n]); msc[4]=mx; }
  __syncthreads();
  if (tid<32) CW[tid]=expf(CW[tid]-msc[4]);
  __syncthreads();
  if (tid==0){ float sm=0.f; for(int n=0;n<32;n++) sm+=CW[n]; msc[5]=1.f/sm; }
  __syncthreads();
  if (tid<32) CW[tid]*=msc[5];
  __syncthreads();
  if (tid<32) WWN[tid]=msc[2]*(msc[1]*AA[tid]+(1.f-msc[1])*CW[tid]);
  __syncthreads();
  // M dealloc + erase/write (paired)
  if (tid<256){
    float2 erv=agld2(&xi[4620+2*tid]);
    float2 wvv=agld2(&xi[5132+2*tid]);
    float er0=sigf(erv.x), er1=sigf(erv.y);
    for (int n=0;n<32;n++){
      float2 m = *(const float2*)&M[(size_t)n*512+2*tid];
      m.x = m.x*PSI[n]*(1.f-WWN[n]*er0) + WWN[n]*wvv.x;
      m.y = m.y*PSI[n]*(1.f-WWN[n]*er1) + WWN[n]*wvv.y;
      *(float2*)&M[(size_t)n*512+2*tid] = m;
    }
  }
  __syncthreads();
  // link matrix (OLD p), then precedence
  for (int ii=0;ii<2;ii++){ int f=tid+512*ii; int i=f>>5, j=f&31;
    float nl=(1.f-WWN[i]-WWN[j])*mL[f]+WWN[i]*PP[j];
    mL[f]=(i==j)?0.f:nl; }
  __syncthreads();
  if (tid==0){ float sw=0.f; for(int n=0;n<32;n++) sw+=WWN[n]; msc[6]=sw; }
  __syncthreads();
  if (tid<32) PP[tid]=(1.f-msc[6])*PP[tid]+WWN[tid];
  __syncthreads();
  // fw/bw sharpened (OLD wr)
  { int r=(tid>>5)&7, i=tid&31; bool isB=(tid>=256);
    float accv=0.f;
    if (!isB){ for (int j=0;j<32;j++) accv += mL[i*32+j]*mwr[r*32+j]; }
    else     { for (int j=0;j<32;j++) accv += mL[j*32+i]*mwr[r*32+j]; }
    float sp = isB? mh[16+r] : mh[8+r];
    float e = expf(sp*logf(accv+1e-6f));
    if (!isB) mfw[r*32+i]=e; else mbw[r*32+i]=e; }
  __syncthreads();
  if (tid<16){ int r=tid&7; float sm=0.f;
    if (tid<8){ for(int n=0;n<32;n++) sm+=mfw[r*32+n]; msc[16+r]=1.f/sm; }
    else      { for(int n=0;n<32;n++) sm+=mbw[r*32+n]; msc[24+r]=1.f/sm; } }
  __syncthreads();
  { int r=(tid>>5)&7, i=tid&31; bool isB=(tid>=256);
    if (!isB) mfw[r*32+i]*=msc[16+r]; else mbw[r*32+i]*=msc[24+r]; }
  __syncthreads();
  // L writeback now (mL region becomes q1b/q2b scratch)
  L_g[tid]=mL[tid]; L_g[tid+512]=mL[tid+512];
  __syncthreads();
  // read content weighting cr (NEW M), TWO heads per M pass
  for (int hp=0; hp<4; hp++){
    if (tid<256){
      #pragma unroll
      for (int rp=0;rp<2;rp++){
        int r=2*hp+rp;
        float* tq1 = rp? q1b : q1;
        float* tq2 = rp? q2b : q2;
        float2 rmv=agld2(&xi[6196+r*512+2*tid]);
        float2 rkv=agld2(&xi[(size_t)r*512+2*tid]);
        float rm0=0.1f+0.9f*sigf(rmv.x), rm1=0.1f+0.9f*sigf(rmv.y);
        tq1[2*tid]=rkv.x*rm0; tq1[2*tid+1]=rkv.y*rm1;
        tq2[2*tid]=rm0;       tq2[2*tid+1]=rm1;
      }
    }
    __syncthreads();
    { int rp=tid>>8, w2=tid&255;
      const float* tq1 = rp? q1b : q1;
      float a=tq1[2*w2], b=tq1[2*w2+1];
      float q=a*a+b*b;
      for (int o=32;o;o>>=1) q+=__shfl_down(q,o,64);
      if ((tid&63)==0) msc[8+(tid>>6)]=q; }
    __syncthreads();
    if (tid<2){ float qq=0.f; for (int i=0;i<4;i++) qq+=msc[8+tid*4+i]; msc[32+tid]=sqrtf(qq); }
    __syncthreads();
    { int rp=tid>>8, rem=tid&255, n=rem>>3, wsub=rem&7;
      const float* tq1 = rp? q1b : q1;
      const float* tq2 = rp? q2b : q2;
      float d=0.f,q=0.f;
      for (int i3=0;i3<32;i3++){ int w=wsub*64+2*i3;
        float2 m = *(const float2*)&M[(size_t)n*512+w];
        float t0=m.x*tq2[w], t1=m.y*tq2[w+1];
        d += tq1[w]*t0 + tq1[w+1]*t1;
        q += t0*t0 + t1*t1;
      }
      for (int o=4;o;o>>=1){ d+=__shfl_down(d,o,8); q+=__shfl_down(q,o,8); }
      if (wsub==0){ int r=2*hp+rp; float cs=d/(msc[32+rp]*sqrtf(q)+1e-6f); mcr[r*32+n]=mh[r]*cs; } }
    __syncthreads();
  }
  if (tid<8){ int r=tid; float mx=-1e30f;
    for (int n=0;n<32;n++) mx=fmaxf(mx,mcr[r*32+n]);
    float sm=0.f;
    for (int n=0;n<32;n++){ float e=expf(mcr[r*32+n]-mx); mcr[r*32+n]=e; sm+=e; }
    float inv=1.f/sm;
    for (int n=0;n<32;n++) mcr[r*32+n]*=inv; }
  __syncthreads();
  if (tid<256){ int r=tid>>5, n=tid&31;
    float v=mpi[r*3]*mbw[r*32+n]+mpi[r*3+1]*mcr[r*32+n]+mpi[r*3+2]*mfw[r*32+n];
    mwrn[tid]=v; wr_g[tid]=v; }
  __syncthreads();
  // reads = wr_new @ M_new (contiguous, paired device stores)
  { int r=tid>>6, wsub=tid&63;
    for (int i3=0;i3<4;i3++){ int w=wsub*8+2*i3;
      float2 acc=make_float2(0.f,0.f);
      for (int n=0;n<32;n++){ float wr=mwrn[r*32+n];
        float2 m = *(const float2*)&M[(size_t)n*512+w];
        acc.x+=wr*m.x; acc.y+=wr*m.y; }
      agst2(&rout[r*512+w], acc); } }
  if (tid<32){ u_g[tid]=UU[tid]; ww_g[tid]=WWN[tid]; p_g[tid]=PP[tid]; }
}

// ---------------------------------------------- persistent whole-recurrence
__global__ __launch_bounds__(TPB, 1)
void dnc_persist(
  const float* __restrict__ sent,
  const float* __restrict__ Wih0, const float* __restrict__ Whh0, const float* __restrict__ b0,
  const float* __restrict__ Wih1, const float* __restrict__ Whh1, const float* __restrict__ b1,
  const float* __restrict__ Wih2, const float* __restrict__ Whh2, const float* __restrict__ b2,
  const float* __restrict__ WXIT, const float* __restrict__ bxi,
  const float* __restrict__ Wout, const float* __restrict__ bout,
  float* __restrict__ yh,
  float* __restrict__ reads,
  float* __restrict__ h0, float* __restrict__ h1,
  float* __restrict__ h2u, float* __restrict__ h2c,
  float* __restrict__ c0p, float* __restrict__ c1p, float* __restrict__ c2p,
  float* __restrict__ zp0, float* __restrict__ zp1, float* __restrict__ zp2,
  float* __restrict__ yp, float* __restrict__ xig,
  float* __restrict__ Mb, float* __restrict__ ug, float* __restrict__ wwg,
  float* __restrict__ pg, float* __restrict__ wrg, float* __restrict__ Lg,
  int* cnt, int* genrep)
{
  extern __shared__ float lds[];
  const int wg  = blockIdx.x;
  const int tid = threadIdx.x;
  const int cg  = wg >> 4, kg  = wg & 15;    // phase A: 64 cols, 288 k
  const int cgB = wg >> 3, kgB = wg & 7;     // phase B/C: 32 cols, 64 k
  const int ycg = wg >> 6, ykg = wg & 63;    // y: 35 cols, 68 k
  const int xc  = tid >> 6, xk = tid & 63;   // phase D layout
  float* stg = lds + oST;
  int seq = 0;

  // ---------------- one-time: weight slices -> LDS ----------------
  for (int f=tid; f<18432; f+=TPB){
    int kk=f>>6, cc=f&63;
    int gk=kg*288+kk, gc=cg*64+cc;
    float v=0.f;
    if (gk<4236) v=Wih0[(size_t)gk*1024+gc];
    else if (gk<4492) v=Whh0[(size_t)(gk-4236)*1024+gc];
    lds[oWA+f]=v;
  }
  for (int f=tid; f<2048; f+=TPB){
    int kk=f>>5, cc=f&31;
    int gk=kgB*64+kk, gc=cgB*32+cc;
    lds[oW1+f] = (gk<256)? Wih1[(size_t)gk*1024+gc] : Whh1[(size_t)(gk-256)*1024+gc];
  }
  for (int f=tid; f<2048; f+=TPB){
    int kk=f>>5, cc=f&31;
    int gk=kgB*64+kk, gc=cgB*32+cc;
    lds[oW2+f] = (gk<256)? Wih2[(size_t)gk*1024+gc] : Whh2[(size_t)(gk-256)*1024+gc];
  }
  for (int f=tid; f<12288; f+=TPB){
    int cl=f>>8, k=f&255; int col=wg*48+cl;
    lds[oWX+f] = (col<10299)? WXIT[(size_t)col*256+k] : 0.f;
  }
  for (int f=tid; f<2380; f+=TPB){
    int kk=f/35, cc=f%35;
    int gk=ykg*68+kk, gc=ycg*35+cc;
    lds[oWY+f] = Wout[(size_t)gk*140+gc];
  }
  __syncthreads();

  #pragma unroll 1
  for (int t=0; t<LSEQ; t++){
    // ========== phase A: z0 partial gemm + y(t-1) partial gemm ==========
    {
      float* sAct = stg;            // [8][288]
      float* sActY= stg+2304;       // [8][68]
      for (int f2=tid; f2<1152; f2+=TPB){
        int s=f2/144, kk=(f2%144)*2; int g=kg*288+kk;
        float2 v;
        if (g<140)       v = *(const float2*)&sent[((size_t)s*512+t)*140+g];
        else if (g<4236) v = agld2(&reads[s*4096+g-140]);
        else if (g<4492) v = agld2(&h0[s*256+(g-4236)]);
        else             v = make_float2(0.f,0.f);
        *(float2*)&sAct[s*288+kk] = v;
      }
      if (t>0) for (int f2=tid; f2<272; f2+=TPB){
        int s=f2/34, kk=(f2%34)*2; int gy=ykg*68+kk;
        float2 v = (gy<256)? agld2(&h2c[s*256+gy]) : agld2(&reads[s*4096+gy-256]);
        *(float2*)&sActY[s*68+kk] = v;
      }
      __syncthreads();
      { int cc=tid&63, s=tid>>6;
        const float* wAl = lds+oWA;
        const float* ac  = sAct + s*288;
        float acc=0.f;
        #pragma unroll 8
        for (int kk=0; kk<288; kk++) acc += wAl[kk*64+cc]*ac[kk];
        float accO = __shfl_xor(acc, 1, 64);
        if (!(tid&1))
          agst2(&zp0[(size_t)(kg*8+s)*1024 + cg*64+cc], make_float2(acc,accO)); }
      if (t>0 && tid<280){ int s=tid/35, cc=tid%35;
        const float* wYl = lds+oWY;
        const float* ac  = sActY + s*68;
        float acc=0.f;
        #pragma unroll 4
        for (int kk=0; kk<68; kk++) acc += wYl[kk*35+cc]*ac[kk];
        agst(&yp[(size_t)(ykg*8+s)*144 + ycg*35+cc], acc); }
    }
    gbar(cnt,genrep,++seq);

    // ========== phase A2: reduce z0 + cell0 -> h0 (wgs 0..63) ==========
    if (wg < 64){
      int s = wg>>3, part = wg&7;
      float* sP = stg;              // [8][128]
      { int j2=tid&15, q=(tid>>4)&3, kp=tid>>6;
        int col = q*256 + part*32 + j2*2;
        float2 v = make_float2(0.f,0.f);
        for (int k2=kp*2; k2<kp*2+2; k2++){
          float2 a = agld2(&zp0[(size_t)(k2*8+s)*1024+col]);
          v.x+=a.x; v.y+=a.y; }
        sP[kp*128 + q*32 + j2*2]   = v.x;
        sP[kp*128 + q*32 + j2*2+1] = v.y; }
      __syncthreads();
      if (tid<32){
        int j = part*32 + tid;
        float zq[4];
        #pragma unroll
        for (int q=0;q<4;q++){ float v=0.f;
          for (int kp=0;kp<8;kp++) v += sP[kp*128+q*32+tid];
          zq[q]=v + b0[q*256+j]; }
        float cold=c0p[s*256+j];
        float cn=sigf(zq[1])*cold + sigf(zq[0])*tanhf(zq[2]);
        float h=sigf(zq[3])*tanhf(cn);
        c0p[s*256+j]=cn;
        float hO=__shfl_xor(h,1,64);
        if (!(tid&1)) agst2(&h0[s*256+j], make_float2(h,hO));
      }
    }
    gbar(cnt,genrep,++seq);

    // ========== phase B: z1 partial gemm ==========
    {
      float* sAct = stg;            // [8][64]
      for (int f2=tid; f2<256; f2+=TPB){
        int s=f2>>5, kk=(f2&31)*2; int g=kgB*64+kk;
        float2 v = (g<256)? agld2(&h0[s*256+g]) : agld2(&h1[s*256+g-256]);
        *(float2*)&sAct[s*64+kk] = v; }
      __syncthreads();
      if (tid<256){ int cc=tid&31, s=tid>>5;
        const float* w1l = lds+oW1;
        const float* ac  = sAct + s*64;
        float acc=0.f;
        #pragma unroll 8
        for (int kk=0; kk<64; kk++) acc += w1l[kk*32+cc]*ac[kk];
        float accO = __shfl_xor(acc, 1, 64);
        if (!(tid&1))
          agst2(&zp1[(size_t)(kgB*8+s)*1024 + cgB*32+cc], make_float2(acc,accO)); }
    }
    gbar(cnt,genrep,++seq);

    // ========== phase B2: reduce z1 + cell1 -> h1 ==========
    if (wg < 64){
      int s = wg>>3, part = wg&7;
      float* sP = stg;              // [8][128]
      { int j2=tid&15, q=(tid>>4)&3, kp=tid>>6;
        float2 a = agld2(&zp1[(size_t)(kp*8+s)*1024 + q*256+part*32+j2*2]);
        sP[kp*128 + q*32 + j2*2]   = a.x;
        sP[kp*128 + q*32 + j2*2+1] = a.y; }
      __syncthreads();
      if (tid<32){
        int j = part*32 + tid;
        float zq[4];
        #pragma unroll
        for (int q=0;q<4;q++){ float v=0.f;
          for (int kp=0;kp<8;kp++) v += sP[kp*128+q*32+tid];
          zq[q]=v + b1[q*256+j]; }
        float cold=c1p[s*256+j];
        float cn=sigf(zq[1])*cold + sigf(zq[0])*tanhf(zq[2]);
        float h=sigf(zq[3])*tanhf(cn);
        c1p[s*256+j]=cn;
        float hO=__shfl_xor(h,1,64);
        if (!(tid&1)) agst2(&h1[s*256+j], make_float2(h,hO));
      }
    }
    gbar(cnt,genrep,++seq);

    // ========== phase C: z2 partial gemm ==========
    {
      float* sAct = stg;
      for (int f2=tid; f2<256; f2+=TPB){
        int s=f2>>5, kk=(f2&31)*2; int g=kgB*64+kk;
        float2 v = (g<256)? agld2(&h1[s*256+g]) : agld2(&h2u[s*256+g-256]);
        *(float2*)&sAct[s*64+kk] = v; }
      __syncthreads();
      if (tid<256){ int cc=tid&31, s=tid>>5;
        const float* w2l = lds+oW2;
        const float* ac  = sAct + s*64;
        float acc=0.f;
        #pragma unroll 8
        for (int kk=0; kk<64; kk++) acc += w2l[kk*32+cc]*ac[kk];
        float accO = __shfl_xor(acc, 1, 64);
        if (!(tid&1))
          agst2(&zp2[(size_t)(kgB*8+s)*1024 + cgB*32+cc], make_float2(acc,accO)); }
    }
    gbar(cnt,genrep,++seq);

    // ========== phase C2: reduce z2 + cell2 -> h2u, h2c ==========
    if (wg < 64){
      int s = wg>>3, part = wg&7;
      float* sP = stg;
      { int j2=tid&15, q=(tid>>4)&3, kp=tid>>6;
        float2 a = agld2(&zp2[(size_t)(kp*8+s)*1024 + q*256+part*32+j2*2]);
        sP[kp*128 + q*32 + j2*2]   = a.x;
        sP[kp*128 + q*32 + j2*2+1] = a.y; }
      __syncthreads();
      if (tid<32){
        int j = part*32 + tid;
        float zq[4];
        #pragma unroll
        for (int q=0;q<4;q++){ float v=0.f;
          for (int kp=0;kp<8;kp++) v += sP[kp*128+q*32+tid];
          zq[q]=v + b2[q*256+j]; }
        float cold=c2p[s*256+j];
        float cn=sigf(zq[1])*cold + sigf(zq[0])*tanhf(zq[2]);
        float h2=sigf(zq[3])*tanhf(cn);
        float hc=fminf(fmaxf(h2,-20.f),20.f);
        c2p[s*256+j]=cn;
        float h2O=__shfl_xor(h2,1,64), hcO=__shfl_xor(hc,1,64);
        if (!(tid&1)){
          agst2(&h2u[s*256+j], make_float2(h2,h2O));
          agst2(&h2c[s*256+j], make_float2(hc,hcO)); }
      }
    }
    gbar(cnt,genrep,++seq);

    // ========== phase D: xi gemm (full K=256, 48 cols/wg) ==========
    {
      float* sA2 = stg;             // [8][260]
      for (int f2=tid; f2<1024; f2+=TPB){
        int s=f2>>7, j=(f2&127)*2;
        float2 v = agld2(&h2c[s*256+j]);
        *(float2*)&sA2[s*260+j] = v; }
      __syncthreads();
      float accx[6][8];
      #pragma unroll
      for (int cc=0;cc<6;cc++)
        #pragma unroll
        for (int s=0;s<8;s++) accx[cc][s]=0.f;
      #pragma unroll
      for (int s=0;s<8;s++){
        float4 a = *reinterpret_cast<const float4*>(&sA2[s*260 + (xk<<2)]);
        #pragma unroll
        for (int cc=0;cc<6;cc++){
          float4 wv = *reinterpret_cast<const float4*>(&lds[oWX + (xc*6+cc)*256 + (xk<<2)]);
          accx[cc][s] += a.x*wv.x + a.y*wv.y + a.z*wv.z + a.w*wv.w;
        }
      }
      #pragma unroll
      for (int o=32;o;o>>=1)
        #pragma unroll
        for (int cc=0;cc<6;cc++)
          #pragma unroll
          for (int s=0;s<8;s++) accx[cc][s]+=__shfl_down(accx[cc][s],o,64);
      if ((tid&63)==0){
        #pragma unroll
        for (int cc=0;cc<6;cc++){
          int col = wg*48 + xc*6 + cc;
          if (col < 10299){
            int pc = ximap(col);
            #pragma unroll
            for (int s=0;s<8;s++) agst(&xig[(size_t)s*XIP+pc], accx[cc][s]+bxi[col]);
          }
        }
      }
    }
    gbar(cnt,genrep,++seq);

    // ========== phase E: memory update (wg<8) + y(t-1) reduce ==========
    if (wg < 8){
      mem_phase(stg, xig + (size_t)wg*XIP, Mb + (size_t)wg*16384,
                ug+wg*32, wwg+wg*32, pg+wg*32, wrg+wg*256, Lg+wg*1024,
                reads + wg*4096);
    } else if (wg < 148 && t > 0){
      int ty = t-1, j = wg-8;
      int s = tid>>6, kg2 = tid&63;
      float v = agld(&yp[(size_t)(kg2*8+s)*144 + j]);
      #pragma unroll
      for (int o=32;o;o>>=1) v += __shfl_down(v,o,64);
      if (kg2==0) yh[((size_t)s*512+ty)*140+j] = v + bout[j];
    }
    gbar(cnt,genrep,++seq);
  }

  // ---------------- y(511): partials + reduce ----------------
  {
    float* sActY = stg;
    for (int f2=tid; f2<272; f2+=TPB){
      int s=f2/34, kk=(f2%34)*2; int gy=ykg*68+kk;
      float2 v = (gy<256)? agld2(&h2c[s*256+gy]) : agld2(&reads[s*4096+gy-256]);
      *(float2*)&sActY[s*68+kk] = v;
    }
    __syncthreads();
    if (tid<280){ int s=tid/35, cc=tid%35;
      const float* wYl = lds+oWY;
      const float* ac  = sActY + s*68;
      float acc=0.f;
      for (int kk=0; kk<68; kk++) acc += wYl[kk*35+cc]*ac[kk];
      agst(&yp[(size_t)(ykg*8+s)*144 + ycg*35+cc], acc); }
  }
  gbar(cnt,genrep,++seq);
  if (wg>=8 && wg<148){
    int j = wg-8;
    int s = tid>>6, kg2 = tid&63;
    float v = agld(&yp[(size_t)(kg2*8+s)*144 + j]);
    #pragma unroll
    for (int o=32;o;o>>=1) v += __shfl_down(v,o,64);
    if (kg2==0) yh[((size_t)s*512+511)*140+j] = v + bout[j];
  }
}

// ---------------------------------------- generic 16-row tiled gemm (lda==K)
__global__ __launch_bounds__(256)
void gemm16(int M, int N, int K,
            const float* __restrict__ A, long long sAb, int lda,
            const float* __restrict__ Bm, long long sBb, int ldb,
            float* __restrict__ C, long long sCb, int ldc,
            const float* __restrict__ bias, int relu)
{
  __shared__ float sAh[16*512];
  const int tid = threadIdx.x;
  const float* Ab = A + (size_t)blockIdx.y*sAb;
  const float* Bb = Bm + (size_t)blockIdx.y*sBb;
  float* Cb = C + (size_t)blockIdx.y*sCb;
  const int m0 = blockIdx.x*16;
  const int tot = 16*K;
  for (int f = tid; f < tot; f += 256) sAh[f] = Ab[(size_t)m0*lda + f];
  __syncthreads();
  int c = (tid & 63)*4; int rg = tid >> 6;
  if (c >= N) return;
  float acc[4][4] = {};
  for (int k=0;k<K;k++){
    float4 bv = *reinterpret_cast<const float4*>(Bb + (size_t)k*ldb + c);
    #pragma unroll
    for (int rr=0;rr<4;rr++){
      float a = sAh[(rg*4+rr)*K + k];
      acc[rr][0] += a*bv.x; acc[rr][1] += a*bv.y; acc[rr][2] += a*bv.z; acc[rr][3] += a*bv.w;
    }
  }
  for (int rr=0;rr<4;rr++){
    int m = m0 + rg*4 + rr;
    #pragma unroll
    for (int e=0;e<4;e++){
      float v = acc[rr][e] + (bias ? bias[c+e] : 0.f);
      if (relu) v = fmaxf(v, 0.f);
      Cb[(size_t)m*ldc + c + e] = v;
    }
  }
}

// ------------------------------------------------------------ bilinear head
__global__ __launch_bounds__(256)
void bilin(const float* __restrict__ s0, const float* __restrict__ t0,
           const float* __restrict__ dis_emb, const int* __restrict__ dht,
           const int* __restrict__ dth, const float* __restrict__ Wb,
           const float* __restrict__ bb, float* __restrict__ out)
{
  __shared__ float sS[BI][33];
  __shared__ float sT[32][152];
  const int tid = threadIdx.x;
  const int bp0 = blockIdx.x*32;
  for (int f = tid; f < 32*BI; f += 256){
    int pp = f / BI, i = f % BI;
    int bp = bp0 + pp;
    float sv, tv;
    if (i < 128){ sv = s0[(size_t)bp*128 + i]; tv = t0[(size_t)bp*128 + i]; }
    else {
      sv = dis_emb[(size_t)dht[bp]*20 + (i-128)];
      tv = dis_emb[(size_t)dth[bp]*20 + (i-128)];
    }
    sS[i][pp] = sv; sT[pp][i] = tv;
  }
  __syncthreads();
  const int ppg = tid >> 5, jb = tid & 31;
  const int pp0 = ppg*4;
  const int k0 = blockIdx.y*49, kend = min(k0+49, RELK);
  for (int k = k0; k < kend; k++){
    const float* Wk = Wb + (size_t)k*BI*BI;
    float acc[4][5];
    #pragma unroll
    for (int a=0;a<4;a++) for (int b=0;b<5;b++) acc[a][b]=0.f;
    for (int i=0;i<BI;i++){
      float sv0 = sS[i][pp0], sv1 = sS[i][pp0+1], sv2 = sS[i][pp0+2], sv3 = sS[i][pp0+3];
      const float* wrow = Wk + i*BI;
      #pragma unroll
      for (int jj=0;jj<5;jj++){
        int j = jb + 32*jj;
        if (j < BI){
          float w = wrow[j];
          acc[0][jj] += sv0*w; acc[1][jj] += sv1*w; acc[2][jj] += sv2*w; acc[3][jj] += sv3*w;
        }
      }
    }
    float dot[4] = {0.f,0.f,0.f,0.f};
    #pragma unroll
    for (int jj=0;jj<5;jj++){
      int j = jb + 32*jj;
      if (j < BI){
        #pragma unroll
        for (int p4=0;p4<4;p4++) dot[p4] += acc[p4][jj]*sT[pp0+p4][j];
      }
    }
    #pragma unroll
    for (int p4=0;p4<4;p4++)
      for (int o=16;o;o>>=1) dot[p4] += __shfl_down(dot[p4], o, 32);
    if (jb == 0){
      #pragma unroll
      for (int p4=0;p4<4;p4++)
        out[(size_t)(bp0+pp0+p4)*RELK + k] = dot[p4] + bb[k];
    }
  }
}

// =========================================================== host launcher
extern "C" void kernel_launch(void* const* d_in, const int* in_sizes, int n_in,
                              void* d_out, int out_size, void* d_ws, size_t ws_size,
                              hipStream_t stream)
{
  (void)in_sizes; (void)n_in; (void)out_size; (void)ws_size;
  const int*   ctx_idx = (const int*)  d_in[0];
  const int*   pos     = (const int*)  d_in[1];
  const int*   nerI    = (const int*)  d_in[2];
  const float* h_map   = (const float*)d_in[5];
  const float* t_map   = (const float*)d_in[6];
  const int*   dht     = (const int*)  d_in[8];
  const int*   dth     = (const int*)  d_in[9];
  const float* wemb    = (const float*)d_in[10];
  const float* eemb    = (const float*)d_in[11];
  const float* nemb    = (const float*)d_in[12];
  const float* demb    = (const float*)d_in[13];
  const float* Wih0    = (const float*)d_in[14];
  const float* Whh0    = (const float*)d_in[15];
  const float* b0      = (const float*)d_in[16];
  const float* Wih1    = (const float*)d_in[17];
  const float* Whh1    = (const float*)d_in[18];
  const float* b1      = (const float*)d_in[19];
  const float* Wih2    = (const float*)d_in[20];
  const float* Whh2    = (const float*)d_in[21];
  const float* b2      = (const float*)d_in[22];
  const float* Wxi     = (const float*)d_in[23];
  const float* bxi     = (const float*)d_in[24];
  const float* Wout    = (const float*)d_in[25];
  const float* bout    = (const float*)d_in[26];
  const float* Wfin    = (const float*)d_in[27];
  const float* bfin    = (const float*)d_in[28];
  const float* Wre     = (const float*)d_in[29];
  const float* bre     = (const float*)d_in[30];
  const float* Wbili   = (const float*)d_in[31];
  const float* bbili   = (const float*)d_in[32];

  float* ws    = (float*)d_ws;
  float* sent  = ws;                    // 573440
  float* yh    = sent + 573440;         // 573440
  float* o256  = yh + 573440;           // 1048576
  float* s0b   = o256 + 1048576;        // 524288
  float* t0b   = s0b + 524288;          // 524288
  float* SB    = t0b + 524288;          // state base
  float* reads = SB + 0;                // 32768
  float* h0    = SB + 32768;            // 2048
  float* h1    = SB + 34816;
  float* h2u   = SB + 36864;
  float* h2c   = SB + 38912;
  float* c0p   = SB + 40960;
  float* c1p   = SB + 43008;
  float* c2p   = SB + 45056;
  float* zp0   = SB + 47104;            // 131072
  float* zp1   = SB + 178176;           // 65536
  float* zp2   = SB + 243712;           // 65536
  float* yp    = SB + 309248;           // 73728
  float* xig   = SB + 382976;           // 8*10312 = 82496
  float* Mb    = SB + 465472;           // 131072
  float* ug    = SB + 596544;           // 256
  float* wwg   = SB + 596800;
  float* pg    = SB + 597056;
  float* wrg   = SB + 597312;           // 2048
  float* Lg    = SB + 599360;           // 8192
  float* barf  = SB + 607552;           // cnt(16) + genrep(32*16) = 528 ints -> 1024
  float* SEnd  = SB + 608576;
  float* WXIT  = SEnd;                  // 2636544
  float* ctxb  = yh;                    // alias: yh dead after gemm16 #1
  int* cnt    = (int*)barf;
  int* genrep = cnt + FSTR;

  hipMemsetAsync(SB, 0, (size_t)608576*sizeof(float), stream);

  hipLaunchKernelGGL(k_tr, dim3(10299), dim3(256), 0, stream,
                     Wxi, Wxi, 10299, 256, 0, 256, (long long)2636544, WXIT);
  hipLaunchKernelGGL(k_sent, dim3((573440+255)/256), dim3(256), 0, stream,
                     ctx_idx, pos, nerI, wemb, eemb, nemb, sent);

  hipFuncSetAttribute(reinterpret_cast<const void*>(dnc_persist),
                      hipFuncAttributeMaxDynamicSharedMemorySize, LDSB);

  hipLaunchKernelGGL(dnc_persist, dim3(NWG), dim3(TPB), LDSB, stream,
                     sent, Wih0, Whh0, b0, Wih1, Whh1, b1, Wih2, Whh2, b2,
                     WXIT, bxi, Wout, bout, yh, reads,
                     h0, h1, h2u, h2c, c0p, c1p, c2p,
                     zp0, zp1, zp2, yp, xig,
                     Mb, ug, wwg, pg, wrg, Lg, cnt, genrep);

  // out = ys @ W_final + b_final          [4096,140]x[140,256]
  hipLaunchKernelGGL(gemm16, dim3(256,1), dim3(256), 0, stream,
                     4096, 256, 140, yh, (long long)0, 140, Wfin, (long long)0, 256,
                     o256, (long long)0, 256, bfin, 0);
  // ctx = relu(out @ W_re + b_re)         [4096,256]x[256,128]
  hipLaunchKernelGGL(gemm16, dim3(256,1), dim3(256), 0, stream,
                     4096, 128, 256, o256, (long long)0, 256, Wre, (long long)0, 128,
                     ctxb, (long long)0, 128, bre, 1);
  // s0 / t0 : per-batch [512,512]x[512,128]
  hipLaunchKernelGGL(gemm16, dim3(32,8), dim3(256), 0, stream,
                     512, 128, 512, h_map, (long long)(512*512), 512,
                     ctxb, (long long)(512*128), 128,
                     s0b, (long long)(512*128), 128, (const float*)nullptr, 0);
  hipLaunchKernelGGL(gemm16, dim3(32,8), dim3(256), 0, stream,
                     512, 128, 512, t_map, (long long)(512*512), 512,
                     ctxb, (long long)(512*128), 128,
                     t0b, (long long)(512*128), 128, (const float*)nullptr, 0);
  // bilinear head
  hipLaunchKernelGGL(bilin, dim3(128,2), dim3(256), 0, stream,
                     s0b, t0b, demb, dht, dth, Wbili, bbili, (float*)d_out);
}

// Round 9
// 90506.097 us; speedup vs baseline: 1.1035x; 1.1035x over previous
//
#include <hip/hip_runtime.h>
#include <math.h>

// ---- static dims ----
#define B8      8
#define LSEQ    512
#define NWG     256
#define TPB     512
#define RELK    97
#define BI      148
#define FSTR    16        // barrier flag stride (ints) = 64B

// LDS float offsets
#define oWA     0         // [288][64]   18432
#define oWX     18432     // [48][256]   12288
#define oWY     30720     // [68][35]     2380
#define oST     33100     // stage/scratch 3752
#define LDSF    36852
#define LDSB    (LDSF*4)  // 147408 B

__device__ __forceinline__ float sigf(float x){
  return (x >= 0.f) ? 1.f/(1.f + expf(-x)) : expf(x)/(1.f + expf(x));
}
__device__ __forceinline__ float spf(float x){
  return (x > 0.f) ? x + log1pf(expf(-x)) : log1pf(expf(x));
}
// agent-scope (L3-coherent) transfers for cross-wg data (verified r5-r8)
__device__ __forceinline__ float agld(const float* p){
  return __hip_atomic_load(p, __ATOMIC_RELAXED, __HIP_MEMORY_SCOPE_AGENT);
}
__device__ __forceinline__ void agst(float* p, float v){
  __hip_atomic_store(p, v, __ATOMIC_RELAXED, __HIP_MEMORY_SCOPE_AGENT);
}

// ---------------------------------------------------------------- sent gather
__global__ __launch_bounds__(256)
void k_sent(const int* __restrict__ cidx, const int* __restrict__ pos,
            const int* __restrict__ ner, const float* __restrict__ wemb,
            const float* __restrict__ eemb, const float* __restrict__ nemb,
            float* __restrict__ sent)
{
  int flat = blockIdx.x*256 + threadIdx.x;
  if (flat >= B8*LSEQ*140) return;
  int d = flat % 140; int bl = flat / 140;
  float v;
  if (d < 100)      v = wemb[(size_t)cidx[bl]*100 + d];
  else if (d < 120) v = eemb[(size_t)pos[bl]*20 + (d-100)];
  else              v = nemb[(size_t)ner[bl]*20 + (d-120)];
  sent[flat] = v;
}

// ------------------------------------------- weight transpose (once, WXI)
__global__ __launch_bounds__(256)
void k_tr(const float* __restrict__ A, const float* __restrict__ Bsrc,
          int N, int K1a, int K1b, int K2, long long total, float* __restrict__ T)
{
  long long i = (long long)blockIdx.x*256 + threadIdx.x;
  if (i >= total) return;
  int k = (int)(i % K2);
  long long c = i / K2;
  float v = 0.f;
  if (k < K1a)            v = A[(size_t)k*N + c];
  else if (k < K1a+K1b)   v = Bsrc[(size_t)(k-K1a)*N + c];
  T[i] = v;
}

// ---------------------------------------------------------- global barrier
// flag-gather (r7-best) + s_sleep(8) backoff to cut poll-traffic congestion.
__device__ __forceinline__ void gbar(int* flags, int* genrep, int seq){
  __syncthreads();
  const int tid = threadIdx.x;
  const int bid = blockIdx.x;
  if (tid == 0){
    asm volatile("s_waitcnt vmcnt(0)" ::: "memory");
    __hip_atomic_store(&flags[bid*FSTR], seq, __ATOMIC_RELAXED, __HIP_MEMORY_SCOPE_AGENT);
  }
  if (bid == 0){
    if (tid < NWG){
      while (__hip_atomic_load(&flags[tid*FSTR], __ATOMIC_RELAXED, __HIP_MEMORY_SCOPE_AGENT) < seq)
        __builtin_amdgcn_s_sleep(8);
    }
    __syncthreads();
    if (tid < NWG)
      __hip_atomic_store(&genrep[tid*FSTR], seq, __ATOMIC_RELAXED, __HIP_MEMORY_SCOPE_AGENT);
  } else if (tid == 0){
    while (__hip_atomic_load(&genrep[bid*FSTR], __ATOMIC_RELAXED, __HIP_MEMORY_SCOPE_AGENT) < seq)
      __builtin_amdgcn_s_sleep(8);
  }
  __syncthreads();
}

// ------------------------------------- per-sample DNC memory addressing phase
// verbatim from the measured-best (85ms) version; scratch <= 3712 floats
__device__ void mem_phase(float* lds, const float* __restrict__ xi,
                          float* __restrict__ M, float* u_g, float* ww_g,
                          float* p_g, float* wr_g, float* L_g, float* rout)
{
  const int tid = threadIdx.x;
  float* mL  = lds;          // [32][32]
  float* mwr = lds+1024;     // [8][32]
  float* mwrn= lds+1280;
  float* mcr = lds+1536;
  float* mfw = lds+1792;
  float* mbw = lds+2048;
  float* PSI = lds+2304;
  float* UU  = lds+2336;
  float* US  = lds+2368;
  float* AA  = lds+2400;
  float* CW  = lds+2432;
  float* WWN = lds+2464;
  float* WWO = lds+2496;
  float* PP  = lds+2528;
  int*   mord= (int*)(lds+2560);   // 32 ints
  float* mh  = lds+2592;           // rb[0..7] sf[8..15] sb[16..23] fg[24..31]
  float* mpi = lds+2624;           // [8][3]
  float* msc = lds+2648;           // 40 scalars
  float* q1  = lds+2688;           // 512
  float* q2  = lds+3200;           // 512 (end 3712)

  if (tid < 8){
    mh[tid]    = 1.f + spf(agld(&xi[4096+tid]));
    mh[8+tid]  = 1.f + spf(agld(&xi[10283+tid]));
    mh[16+tid] = 1.f + spf(agld(&xi[10291+tid]));
    mh[24+tid] = sigf(agld(&xi[5641+tid]));
    float e0=agld(&xi[5651+3*tid]), e1=agld(&xi[5652+3*tid]), e2=agld(&xi[5653+3*tid]);
    float mx=fmaxf(e0,fmaxf(e1,e2));
    float x0=expf(e0-mx), x1=expf(e1-mx), x2=expf(e2-mx);
    float inv=1.f/(x0+x1+x2);
    mpi[tid*3]=x0*inv; mpi[tid*3+1]=x1*inv; mpi[tid*3+2]=x2*inv;
  }
  if (tid==0){ msc[0]=1.f+spf(agld(&xi[4616])); msc[1]=sigf(agld(&xi[5649])); msc[2]=sigf(agld(&xi[5650])); }
  if (tid<32){ UU[tid]=u_g[tid]; WWO[tid]=ww_g[tid]; PP[tid]=p_g[tid]; }
  if (tid<256) mwr[tid]=wr_g[tid];
  mL[tid]=L_g[tid]; mL[tid+512]=L_g[tid+512];
  { float wm = 0.1f+0.9f*sigf(agld(&xi[5675+tid])); q1[tid]=agld(&xi[4104+tid])*wm; q2[tid]=wm; }
  __syncthreads();

  if (tid<32){
    float psi=1.f;
    #pragma unroll
    for (int r=0;r<8;r++) psi *= (1.f - mh[24+r]*mwr[r*32+tid]);
    PSI[tid]=psi;
    float uo=UU[tid], wo=WWO[tid];
    UU[tid]=(uo+wo-uo*wo)*psi;
  }
  __syncthreads();
  if (tid<32){
    float un=UU[tid]; int rank=0;
    for (int m=0;m<32;m++){ float um=UU[m]; rank += (um<un)||(um==un && m<tid); }
    mord[rank]=tid;
  }
  __syncthreads();
  if (tid<32) US[tid]=UU[mord[tid]];
  __syncthreads();
  if (tid==0){ float cp=1.f; for (int j=0;j<32;j++){ AA[mord[j]]=(1.f-US[j])*cp; cp*=US[j]; } }
  __syncthreads();

  { float q=q1[tid]*q1[tid];
    for (int o=32;o;o>>=1) q += __shfl_down(q,o,64);
    if ((tid&63)==0) msc[8+(tid>>6)]=q; }
  __syncthreads();
  if (tid==0){ float q=0.f; for (int i=0;i<8;i++) q+=msc[8+i]; msc[3]=sqrtf(q); }
  __syncthreads();
  { int n=tid>>4, wsub=tid&15;
    float d=0.f,q=0.f;
    for (int i=0;i<32;i++){ int w=wsub+16*i; float m=M[(size_t)n*512+w]; float t2=m*q2[w]; d+=q1[w]*t2; q+=t2*t2; }
    for (int o=8;o;o>>=1){ d+=__shfl_down(d,o,16); q+=__shfl_down(q,o,16); }
    if (wsub==0){ float cs=d/(msc[3]*sqrtf(q)+1e-6f); CW[n]=msc[0]*cs; } }
  __syncthreads();
  if (tid==0){ float mx=-1e30f; for(int n=0;n<32;n++) mx=fmaxf(mx,CW[n]); msc[4]=mx; }
  __syncthreads();
  if (tid<32) CW[tid]=expf(CW[tid]-msc[4]);
  __syncthreads();
  if (tid==0){ float sm=0.f; for(int n=0;n<32;n++) sm+=CW[n]; msc[5]=1.f/sm; }
  __syncthreads();
  if (tid<32) CW[tid]*=msc[5];
  __syncthreads();
  if (tid<32) WWN[tid]=msc[2]*(msc[1]*AA[tid]+(1.f-msc[1])*CW[tid]);
  __syncthreads();
  { float er=sigf(agld(&xi[4617+tid])); float wv=agld(&xi[5129+tid]);
    for (int n=0;n<32;n++){ size_t idx=(size_t)n*512+tid; float m=M[idx];
      M[idx]=m*PSI[n]*(1.f-WWN[n]*er)+WWN[n]*wv; } }
  __syncthreads();
  for (int ii=0;ii<2;ii++){ int f=tid+512*ii; int i=f>>5, j=f&31;
    float nl=(1.f-WWN[i]-WWN[j])*mL[f]+WWN[i]*PP[j];
    mL[f]=(i==j)?0.f:nl; }
  __syncthreads();
  if (tid==0){ float sw=0.f; for(int n=0;n<32;n++) sw+=WWN[n]; msc[6]=sw; }
  __syncthreads();
  if (tid<32) PP[tid]=(1.f-msc[6])*PP[tid]+WWN[tid];
  __syncthreads();
  { int r=(tid>>5)&7, i=tid&31; bool isB=(tid>=256);
    float accv=0.f;
    if (!isB){ for (int j=0;j<32;j++) accv += mL[i*32+j]*mwr[r*32+j]; }
    else     { for (int j=0;j<32;j++) accv += mL[j*32+i]*mwr[r*32+j]; }
    float sp = isB? mh[16+r] : mh[8+r];
    float e = expf(sp*logf(accv+1e-6f));
    if (!isB) mfw[r*32+i]=e; else mbw[r*32+i]=e; }
  __syncthreads();
  if (tid<16){ int r=tid&7; float sm=0.f;
    if (tid<8){ for(int n=0;n<32;n++) sm+=mfw[r*32+n]; msc[16+r]=1.f/sm; }
    else      { for(int n=0;n<32;n++) sm+=mbw[r*32+n]; msc[24+r]=1.f/sm; } }
  __syncthreads();
  { int r=(tid>>5)&7, i=tid&31; bool isB=(tid>=256);
    if (!isB) mfw[r*32+i]*=msc[16+r]; else mbw[r*32+i]*=msc[24+r]; }
  __syncthreads();
  for (int r=0;r<8;r++){
    { float rm=0.1f+0.9f*sigf(agld(&xi[6187+r*512+tid]));
      q1[tid]=agld(&xi[r*512+tid])*rm; q2[tid]=rm; }
    __syncthreads();
    { float q=q1[tid]*q1[tid];
      for (int o=32;o;o>>=1) q+=__shfl_down(q,o,64);
      if ((tid&63)==0) msc[8+(tid>>6)]=q; }
    __syncthreads();
    if (tid==0){ float qq=0.f; for(int i=0;i<8;i++) qq+=msc[8+i]; msc[32]=sqrtf(qq); }
    __syncthreads();
    { int n=tid>>4, wsub=tid&15;
      float d=0.f,q=0.f;
      for (int i=0;i<32;i++){ int w=wsub+16*i; float m=M[(size_t)n*512+w]; float t2=m*q2[w]; d+=q1[w]*t2; q+=t2*t2; }
      for (int o=8;o;o>>=1){ d+=__shfl_down(d,o,16); q+=__shfl_down(q,o,16); }
      if (wsub==0){ float cs=d/(msc[32]*sqrtf(q)+1e-6f); mcr[r*32+n]=mh[r]*cs; } }
    __syncthreads();
  }
  if (tid<8){ int r=tid; float mx=-1e30f;
    for (int n=0;n<32;n++) mx=fmaxf(mx,mcr[r*32+n]);
    float sm=0.f;
    for (int n=0;n<32;n++){ float e=expf(mcr[r*32+n]-mx); mcr[r*32+n]=e; sm+=e; }
    float inv=1.f/sm;
    for (int n=0;n<32;n++) mcr[r*32+n]*=inv; }
  __syncthreads();
  if (tid<256){ int r=tid>>5, n=tid&31;
    float v=mpi[r*3]*mbw[r*32+n]+mpi[r*3+1]*mcr[r*32+n]+mpi[r*3+2]*mfw[r*32+n];
    mwrn[tid]=v; wr_g[tid]=v; }
  __syncthreads();
  { int r=tid>>6, wsub=tid&63;
    for (int i2=0;i2<8;i2++){ int w=wsub+64*i2;
      float accv=0.f;
      for (int n=0;n<32;n++) accv+=mwrn[r*32+n]*M[(size_t)n*512+w];
      agst(&rout[r*512+w], accv); } }
  if (tid<32){ u_g[tid]=UU[tid]; ww_g[tid]=WWN[tid]; p_g[tid]=PP[tid]; }
  L_g[tid]=mL[tid]; L_g[tid+512]=mL[tid+512];
}

// ---------------------------------------------- persistent whole-recurrence
// 6 barriers/step: A (z0+y partials) | A2 (cell0) | B' (z1+cell1) |
// C' (z2+cell2) | D (xi) | E (memory + y-reduce)
__global__ __launch_bounds__(TPB, 1)
void dnc_persist(
  const float* __restrict__ sent,
  const float* __restrict__ Wih0, const float* __restrict__ Whh0, const float* __restrict__ b0,
  const float* __restrict__ Wih1, const float* __restrict__ Whh1, const float* __restrict__ b1,
  const float* __restrict__ Wih2, const float* __restrict__ Whh2, const float* __restrict__ b2,
  const float* __restrict__ WXIT, const float* __restrict__ bxi,
  const float* __restrict__ Wout, const float* __restrict__ bout,
  float* __restrict__ yh,
  float* __restrict__ reads,
  float* __restrict__ h0, float* __restrict__ h1,
  float* __restrict__ h2u, float* __restrict__ h2c,
  float* __restrict__ c0p, float* __restrict__ c1p, float* __restrict__ c2p,
  float* __restrict__ zp0,
  float* __restrict__ yp, float* __restrict__ xig,
  float* __restrict__ Mb, float* __restrict__ ug, float* __restrict__ wwg,
  float* __restrict__ pg, float* __restrict__ wrg, float* __restrict__ Lg,
  int* flags, int* genrep)
{
  extern __shared__ float lds[];
  const int wg  = blockIdx.x;
  const int tid = threadIdx.x;
  const int cg  = wg >> 4, kg  = wg & 15;    // phase A: 16 col-groups x 16 k-parts
  const int ycg = wg >> 6, ykg = wg & 63;    // y: 35 cols, 68 k
  const int xc  = tid >> 6, xk = tid & 63;   // phase D layout
  const int lane = tid & 63, sw = tid >> 6;  // wave-per-sample layout
  float* stg = lds + oST;
  int seq = 0;

  // ---------------- one-time: weight slices -> LDS / registers ----------------
  for (int f=tid; f<18432; f+=TPB){          // WA [kk][64cc]
    int kk=f>>6, cc=f&63;
    int gk=kg*288+kk, gc=cg*64+cc;
    float v=0.f;
    if (gk<4236) v=Wih0[(size_t)gk*1024+gc];
    else if (gk<4492) v=Whh0[(size_t)(gk-4236)*1024+gc];
    lds[oWA+f]=v;
  }
  for (int f=tid; f<12288; f+=TPB){          // WXI [cl][256k]
    int cl=f>>8, k=f&255; int col=wg*48+cl;
    lds[oWX+f] = (col<10299)? WXIT[(size_t)col*256+k] : 0.f;
  }
  for (int f=tid; f<2380; f+=TPB){           // WY [kk][35cc]
    int kk=f/35, cc=f%35;
    int gk=ykg*68+kk, gc=ycg*35+cc;
    lds[oWY+f] = Wout[(size_t)gk*140+gc];
  }
  // per-thread register weights for B'/C' (unit = wg, gate cols g*256+wg)
  float w1r[32], w2r[32];
  #pragma unroll
  for (int g=0; g<4; g++)
    #pragma unroll
    for (int i=0; i<8; i++){
      int kk = lane + 64*i;
      w1r[g*8+i] = (kk<256)? Wih1[(size_t)kk*1024 + g*256+wg]
                           : Whh1[(size_t)(kk-256)*1024 + g*256+wg];
      w2r[g*8+i] = (kk<256)? Wih2[(size_t)kk*1024 + g*256+wg]
                           : Whh2[(size_t)(kk-256)*1024 + g*256+wg];
    }
  float bb0[4], bb1[4], bb2[4];
  #pragma unroll
  for (int g=0; g<4; g++){
    bb0[g]=b0[g*256+wg]; bb1[g]=b1[g*256+wg]; bb2[g]=b2[g*256+wg];
  }
  __syncthreads();

  #pragma unroll 1
  for (int t=0; t<LSEQ; t++){
    const int hb = t&1, hw = hb^1;   // h1/h2u read buffer / write buffer

    // ========== phase A: z0 partial gemm + y(t-1) partial gemm ==========
    {
      float* sAct = stg;            // [8][288]
      float* sActY= stg+2304;       // [8][68]
      for (int f=tid; f<2304; f+=TPB){
        int s=f/288, kk=f%288; int g=kg*288+kk;
        float v;
        if (g<140)       v = sent[((size_t)s*512+t)*140+g];
        else if (g<4236) v = agld(&reads[s*4096+g-140]);
        else if (g<4492) v = agld(&h0[s*256+(g-4236)]);
        else             v = 0.f;
        sAct[f]=v;
      }
      if (t>0) for (int f=tid; f<544; f+=TPB){
        int s=f/68, kk=f%68; int gy=ykg*68+kk;
        sActY[f] = (gy<256)? agld(&h2c[s*256+gy]) : agld(&reads[s*4096+gy-256]);
      }
      __syncthreads();
      { int cc=tid&63, s=tid>>6;
        const float* wAl = lds+oWA;
        const float* ac  = sAct + s*288;
        float acc=0.f;
        #pragma unroll 8
        for (int kk=0; kk<288; kk++) acc += wAl[kk*64+cc]*ac[kk];
        agst(&zp0[(size_t)(kg*8+s)*1024 + cg*64+cc], acc); }
      if (t>0 && tid<280){ int s=tid/35, cc=tid%35;
        const float* wYl = lds+oWY;
        const float* ac  = sActY + s*68;
        float acc=0.f;
        #pragma unroll 4
        for (int kk=0; kk<68; kk++) acc += wYl[kk*35+cc]*ac[kk];
        agst(&yp[(size_t)(ykg*8+s)*144 + ycg*35+cc], acc); }
    }
    gbar(flags,genrep,++seq);

    // ========== phase A2: reduce z0 (16 parts) + cell0 -> h0; unit = wg ====
    {
      int g = lane>>4, p = lane&15;
      float val = agld(&zp0[(size_t)(p*8+sw)*1024 + g*256 + wg]);
      #pragma unroll
      for (int o=8;o;o>>=1) val += __shfl_down(val,o,16);
      float zi=__shfl(val, 0,64), zf=__shfl(val,16,64);
      float zg=__shfl(val,32,64), zo=__shfl(val,48,64);
      if (lane==0){
        zi+=bb0[0]; zf+=bb0[1]; zg+=bb0[2]; zo+=bb0[3];
        float cold=c0p[sw*256+wg];
        float cn=sigf(zf)*cold + sigf(zi)*tanhf(zg);
        float h=sigf(zo)*tanhf(cn);
        c0p[sw*256+wg]=cn;
        agst(&h0[sw*256+wg], h);
      }
    }
    gbar(flags,genrep,++seq);

    // ========== phase B': z1 (K=512) + cell1 -> h1; unit = wg ============
    {
      const float* h1r = h1 + (size_t)hb*2048;
      float a[8];
      #pragma unroll
      for (int i=0;i<8;i++){
        int k = lane + 64*i;
        a[i] = (i<4)? agld(&h0[sw*256+k]) : agld(&h1r[sw*256+k-256]);
      }
      float acc[4]={0.f,0.f,0.f,0.f};
      #pragma unroll
      for (int i=0;i<8;i++)
        #pragma unroll
        for (int g=0;g<4;g++) acc[g] += a[i]*w1r[g*8+i];
      #pragma unroll
      for (int o=32;o;o>>=1)
        #pragma unroll
        for (int g=0;g<4;g++) acc[g]+=__shfl_down(acc[g],o,64);
      if (lane==0){
        float zi=acc[0]+bb1[0], zf=acc[1]+bb1[1], zg=acc[2]+bb1[2], zo=acc[3]+bb1[3];
        float cold=c1p[sw*256+wg];
        float cn=sigf(zf)*cold + sigf(zi)*tanhf(zg);
        float h=sigf(zo)*tanhf(cn);
        c1p[sw*256+wg]=cn;
        agst(&h1[(size_t)hw*2048 + sw*256+wg], h);
      }
    }
    gbar(flags,genrep,++seq);

    // ========== phase C': z2 (K=512) + cell2 -> h2u, h2c; unit = wg ======
    {
      const float* h1c = h1 + (size_t)hw*2048;   // current h1
      const float* h2r = h2u + (size_t)hb*2048;  // previous h2
      float a[8];
      #pragma unroll
      for (int i=0;i<8;i++){
        int k = lane + 64*i;
        a[i] = (i<4)? agld(&h1c[sw*256+k]) : agld(&h2r[sw*256+k-256]);
      }
      float acc[4]={0.f,0.f,0.f,0.f};
      #pragma unroll
      for (int i=0;i<8;i++)
        #pragma unroll
        for (int g=0;g<4;g++) acc[g] += a[i]*w2r[g*8+i];
      #pragma unroll
      for (int o=32;o;o>>=1)
        #pragma unroll
        for (int g=0;g<4;g++) acc[g]+=__shfl_down(acc[g],o,64);
      if (lane==0){
        float zi=acc[0]+bb2[0], zf=acc[1]+bb2[1], zg=acc[2]+bb2[2], zo=acc[3]+bb2[3];
        float cold=c2p[sw*256+wg];
        float cn=sigf(zf)*cold + sigf(zi)*tanhf(zg);
        float h2=sigf(zo)*tanhf(cn);
        float hc=fminf(fmaxf(h2,-20.f),20.f);
        c2p[sw*256+wg]=cn;
        agst(&h2u[(size_t)hw*2048 + sw*256+wg], h2);
        agst(&h2c[sw*256+wg], hc);
      }
    }
    gbar(flags,genrep,++seq);

    // ========== phase D: xi gemm (full K=256, 48 cols/wg) ==========
    {
      float* sA2 = stg;             // [8][260]
      for (int f=tid; f<2048; f+=TPB){ int s=f>>8, j=f&255;
        sA2[s*260+j] = agld(&h2c[s*256+j]); }
      __syncthreads();
      float accx[6][8];
      #pragma unroll
      for (int cc=0;cc<6;cc++)
        #pragma unroll
        for (int s=0;s<8;s++) accx[cc][s]=0.f;
      #pragma unroll
      for (int s=0;s<8;s++){
        float4 a = *reinterpret_cast<const float4*>(&sA2[s*260 + (xk<<2)]);
        #pragma unroll
        for (int cc=0;cc<6;cc++){
          float4 wv = *reinterpret_cast<const float4*>(&lds[oWX + (xc*6+cc)*256 + (xk<<2)]);
          accx[cc][s] += a.x*wv.x + a.y*wv.y + a.z*wv.z + a.w*wv.w;
        }
      }
      #pragma unroll
      for (int o=32;o;o>>=1)
        #pragma unroll
        for (int cc=0;cc<6;cc++)
          #pragma unroll
          for (int s=0;s<8;s++) accx[cc][s]+=__shfl_down(accx[cc][s],o,64);
      if ((tid&63)==0){
        #pragma unroll
        for (int cc=0;cc<6;cc++){
          int col = wg*48 + xc*6 + cc;
          if (col < 10299){
            #pragma unroll
            for (int s=0;s<8;s++) agst(&xig[(size_t)s*10299+col], accx[cc][s]+bxi[col]);
          }
        }
      }
    }
    gbar(flags,genrep,++seq);

    // ========== phase E: memory update (wg<8) + y(t-1) reduce ==========
    if (wg < 8){
      mem_phase(stg, xig + (size_t)wg*10299, Mb + (size_t)wg*16384,
                ug+wg*32, wwg+wg*32, pg+wg*32, wrg+wg*256, Lg+wg*1024,
                reads + wg*4096);
    } else if (wg < 148 && t > 0){
      int ty = t-1, j = wg-8;
      int s = tid>>6, kg2 = tid&63;
      float v = agld(&yp[(size_t)(kg2*8+s)*144 + j]);
      #pragma unroll
      for (int o=32;o;o>>=1) v += __shfl_down(v,o,64);
      if (kg2==0) yh[((size_t)s*512+ty)*140+j] = v + bout[j];
    }
    gbar(flags,genrep,++seq);
  }

  // ---------------- y(511): partials + reduce ----------------
  {
    float* sActY = stg;
    for (int f=tid; f<544; f+=TPB){
      int s=f/68, kk=f%68; int gy=ykg*68+kk;
      sActY[f] = (gy<256)? agld(&h2c[s*256+gy]) : agld(&reads[s*4096+gy-256]);
    }
    __syncthreads();
    if (tid<280){ int s=tid/35, cc=tid%35;
      const float* wYl = lds+oWY;
      const float* ac  = sActY + s*68;
      float acc=0.f;
      for (int kk=0; kk<68; kk++) acc += wYl[kk*35+cc]*ac[kk];
      agst(&yp[(size_t)(ykg*8+s)*144 + ycg*35+cc], acc); }
  }
  gbar(flags,genrep,++seq);
  if (wg>=8 && wg<148){
    int j = wg-8;
    int s = tid>>6, kg2 = tid&63;
    float v = agld(&yp[(size_t)(kg2*8+s)*144 + j]);
    #pragma unroll
    for (int o=32;o;o>>=1) v += __shfl_down(v,o,64);
    if (kg2==0) yh[((size_t)s*512+511)*140+j] = v + bout[j];
  }
}

// ---------------------------------------- generic 16-row tiled gemm (lda==K)
__global__ __launch_bounds__(256)
void gemm16(int M, int N, int K,
            const float* __restrict__ A, long long sAb, int lda,
            const float* __restrict__ Bm, long long sBb, int ldb,
            float* __restrict__ C, long long sCb, int ldc,
            const float* __restrict__ bias, int relu)
{
  __shared__ float sAh[16*512];
  const int tid = threadIdx.x;
  const float* Ab = A + (size_t)blockIdx.y*sAb;
  const float* Bb = Bm + (size_t)blockIdx.y*sBb;
  float* Cb = C + (size_t)blockIdx.y*sCb;
  const int m0 = blockIdx.x*16;
  const int tot = 16*K;
  for (int f = tid; f < tot; f += 256) sAh[f] = Ab[(size_t)m0*lda + f];
  __syncthreads();
  int c = (tid & 63)*4; int rg = tid >> 6;
  if (c >= N) return;
  float acc[4][4] = {};
  for (int k=0;k<K;k++){
    float4 bv = *reinterpret_cast<const float4*>(Bb + (size_t)k*ldb + c);
    #pragma unroll
    for (int rr=0;rr<4;rr++){
      float a = sAh[(rg*4+rr)*K + k];
      acc[rr][0] += a*bv.x; acc[rr][1] += a*bv.y; acc[rr][2] += a*bv.z; acc[rr][3] += a*bv.w;
    }
  }
  for (int rr=0;rr<4;rr++){
    int m = m0 + rg*4 + rr;
    #pragma unroll
    for (int e=0;e<4;e++){
      float v = acc[rr][e] + (bias ? bias[c+e] : 0.f);
      if (relu) v = fmaxf(v, 0.f);
      Cb[(size_t)m*ldc + c + e] = v;
    }
  }
}

// ------------------------------------------------------------ bilinear head
__global__ __launch_bounds__(256)
void bilin(const float* __restrict__ s0, const float* __restrict__ t0,
           const float* __restrict__ dis_emb, const int* __restrict__ dht,
           const int* __restrict__ dth, const float* __restrict__ Wb,
           const float* __restrict__ bb, float* __restrict__ out)
{
  __shared__ float sS[BI][33];
  __shared__ float sT[32][152];
  const int tid = threadIdx.x;
  const int bp0 = blockIdx.x*32;
  for (int f = tid; f < 32*BI; f += 256){
    int pp = f / BI, i = f % BI;
    int bp = bp0 + pp;
    float sv, tv;
    if (i < 128){ sv = s0[(size_t)bp*128 + i]; tv = t0[(size_t)bp*128 + i]; }
    else {
      sv = dis_emb[(size_t)dht[bp]*20 + (i-128)];
      tv = dis_emb[(size_t)dth[bp]*20 + (i-128)];
    }
    sS[i][pp] = sv; sT[pp][i] = tv;
  }
  __syncthreads();
  const int ppg = tid >> 5, jb = tid & 31;
  const int pp0 = ppg*4;
  const int k0 = blockIdx.y*49, kend = min(k0+49, RELK);
  for (int k = k0; k < kend; k++){
    const float* Wk = Wb + (size_t)k*BI*BI;
    float acc[4][5];
    #pragma unroll
    for (int a=0;a<4;a++) for (int b=0;b<5;b++) acc[a][b]=0.f;
    for (int i=0;i<BI;i++){
      float sv0 = sS[i][pp0], sv1 = sS[i][pp0+1], sv2 = sS[i][pp0+2], sv3 = sS[i][pp0+3];
      const float* wrow = Wk + i*BI;
      #pragma unroll
      for (int jj=0;jj<5;jj++){
        int j = jb + 32*jj;
        if (j < BI){
          float w = wrow[j];
          acc[0][jj] += sv0*w; acc[1][jj] += sv1*w; acc[2][jj] += sv2*w; acc[3][jj] += sv3*w;
        }
      }
    }
    float dot[4] = {0.f,0.f,0.f,0.f};
    #pragma unroll
    for (int jj=0;jj<5;jj++){
      int j = jb + 32*jj;
      if (j < BI){
        #pragma unroll
        for (int p4=0;p4<4;p4++) dot[p4] += acc[p4][jj]*sT[pp0+p4][j];
      }
    }
    #pragma unroll
    for (int p4=0;p4<4;p4++)
      for (int o=16;o;o>>=1) dot[p4] += __shfl_down(dot[p4], o, 32);
    if (jb == 0){
      #pragma unroll
      for (int p4=0;p4<4;p4++)
        out[(size_t)(bp0+pp0+p4)*RELK + k] = dot[p4] + bb[k];
    }
  }
}

// =========================================================== host launcher
extern "C" void kernel_launch(void* const* d_in, const int* in_sizes, int n_in,
                              void* d_out, int out_size, void* d_ws, size_t ws_size,
                              hipStream_t stream)
{
  (void)in_sizes; (void)n_in; (void)out_size; (void)ws_size;
  const int*   ctx_idx = (const int*)  d_in[0];
  const int*   pos     = (const int*)  d_in[1];
  const int*   nerI    = (const int*)  d_in[2];
  const float* h_map   = (const float*)d_in[5];
  const float* t_map   = (const float*)d_in[6];
  const int*   dht     = (const int*)  d_in[8];
  const int*   dth     = (const int*)  d_in[9];
  const float* wemb    = (const float*)d_in[10];
  const float* eemb    = (const float*)d_in[11];
  const float* nemb    = (const float*)d_in[12];
  const float* demb    = (const float*)d_in[13];
  const float* Wih0    = (const float*)d_in[14];
  const float* Whh0    = (const float*)d_in[15];
  const float* b0      = (const float*)d_in[16];
  const float* Wih1    = (const float*)d_in[17];
  const float* Whh1    = (const float*)d_in[18];
  const float* b1      = (const float*)d_in[19];
  const float* Wih2    = (const float*)d_in[20];
  const float* Whh2    = (const float*)d_in[21];
  const float* b2      = (const float*)d_in[22];
  const float* Wxi     = (const float*)d_in[23];
  const float* bxi     = (const float*)d_in[24];
  const float* Wout    = (const float*)d_in[25];
  const float* bout    = (const float*)d_in[26];
  const float* Wfin    = (const float*)d_in[27];
  const float* bfin    = (const float*)d_in[28];
  const float* Wre     = (const float*)d_in[29];
  const float* bre     = (const float*)d_in[30];
  const float* Wbili   = (const float*)d_in[31];
  const float* bbili   = (const float*)d_in[32];

  float* ws    = (float*)d_ws;
  float* sent  = ws;                    // 573440
  float* yh    = sent + 573440;         // 573440
  float* o256  = yh + 573440;           // 1048576
  float* s0b   = o256 + 1048576;        // 524288
  float* t0b   = s0b + 524288;          // 524288
  float* SB    = t0b + 524288;          // state base
  float* reads = SB + 0;                // 32768
  float* h0    = SB + 32768;            // 2048
  float* h1    = SB + 34816;            // 2x2048
  float* h2u   = SB + 38912;            // 2x2048
  float* h2c   = SB + 43008;            // 2048
  float* c0p   = SB + 45056;            // 2048
  float* c1p   = SB + 47104;
  float* c2p   = SB + 49152;
  float* zp0   = SB + 51200;            // 131072
  float* yp    = SB + 182272;           // 73728
  float* xig   = SB + 256000;           // 82392
  float* Mb    = SB + 338392;           // 131072
  float* ug    = SB + 469464;           // 256
  float* wwg   = SB + 469720;
  float* pg    = SB + 469976;
  float* wrg   = SB + 470232;           // 2048
  float* Lg    = SB + 472280;           // 8192
  float* barf  = SB + 480472;           // flags 4096 + genrep 4096 ints
  float* SEnd  = SB + 488664;
  float* WXIT  = SEnd;                  // 2636544
  float* ctxb  = yh;                    // alias: yh dead after gemm16 #1
  int* flags  = (int*)barf;
  int* genrep = flags + 256*FSTR;

  hipMemsetAsync(SB, 0, (size_t)488664*sizeof(float), stream);

  hipLaunchKernelGGL(k_tr, dim3(10299), dim3(256), 0, stream,
                     Wxi, Wxi, 10299, 256, 0, 256, (long long)2636544, WXIT);
  hipLaunchKernelGGL(k_sent, dim3((573440+255)/256), dim3(256), 0, stream,
                     ctx_idx, pos, nerI, wemb, eemb, nemb, sent);

  hipFuncSetAttribute(reinterpret_cast<const void*>(dnc_persist),
                      hipFuncAttributeMaxDynamicSharedMemorySize, LDSB);

  hipLaunchKernelGGL(dnc_persist, dim3(NWG), dim3(TPB), LDSB, stream,
                     sent, Wih0, Whh0, b0, Wih1, Whh1, b1, Wih2, Whh2, b2,
                     WXIT, bxi, Wout, bout, yh, reads,
                     h0, h1, h2u, h2c, c0p, c1p, c2p,
                     zp0, yp, xig,
                     Mb, ug, wwg, pg, wrg, Lg, flags, genrep);

  // out = ys @ W_final + b_final          [4096,140]x[140,256]
  hipLaunchKernelGGL(gemm16, dim3(256,1), dim3(256), 0, stream,
                     4096, 256, 140, yh, (long long)0, 140, Wfin, (long long)0, 256,
                     o256, (long long)0, 256, bfin, 0);
  // ctx = relu(out @ W_re + b_re)         [4096,256]x[256,128]
  hipLaunchKernelGGL(gemm16, dim3(256,1), dim3(256), 0, stream,
                     4096, 128, 256, o256, (long long)0, 256, Wre, (long long)0, 128,
                     ctxb, (long long)0, 128, bre, 1);
  // s0 / t0 : per-batch [512,512]x[512,128]
  hipLaunchKernelGGL(gemm16, dim3(32,8), dim3(256), 0, stream,
                     512, 128, 512, h_map, (long long)(512*512), 512,
                     ctxb, (long long)(512*128), 128,
                     s0b, (long long)(512*128), 128, (const float*)nullptr, 0);
  hipLaunchKernelGGL(gemm16, dim3(32,8), dim3(256), 0, stream,
                     512, 128, 512, t_map, (long long)(512*512), 512,
                     ctxb, (long long)(512*128), 128,
                     t0b, (long long)(512*128), 128, (const float*)nullptr, 0);
  // bilinear head
  hipLaunchKernelGGL(bilin, dim3(128,2), dim3(256), 0, stream,
                     s0b, t0b, demb, dht, dth, Wbili, bbili, (float*)d_out);
}